// Round 1
// baseline (839.861 us; speedup 1.0000x reference)
//
#include <hip/hip_runtime.h>

#define DIM 128
#define GAMMA 12.0f

// One 64-lane wave per edge; lane i handles dims 2i, 2i+1 (float2, coalesced).
__global__ __launch_bounds__(256) void transe_edge_kernel(
    const float* __restrict__ node_emb,
    const float* __restrict__ edge_emb,
    const int* __restrict__ src,
    const int* __restrict__ dst,
    float* __restrict__ out,
    int E)
{
    int wave = (blockIdx.x * (int)blockDim.x + (int)threadIdx.x) >> 6;
    int lane = threadIdx.x & 63;
    if (wave >= E) return;

    int s = src[wave];
    int t = dst[wave];

    const float2* hp = (const float2*)(node_emb + (size_t)s * DIM);
    const float2* tp = (const float2*)(node_emb + (size_t)t * DIM);
    const float2* rp = (const float2*)(edge_emb + (size_t)wave * DIM);

    float2 h  = hp[lane];
    float2 r  = rp[lane];
    float2 tl = tp[lane];

    float tx = h.x + r.x;
    float ty = h.y + r.y;
    float dx = tx - tl.x;
    float dy = ty - tl.y;
    float sq = dx * dx + dy * dy;

    // Butterfly reduction across the full 64-lane wave.
    #pragma unroll
    for (int off = 32; off > 0; off >>= 1)
        sq += __shfl_xor(sq, off, 64);

    float dist  = sqrtf(sq);
    float score = 1.0f / (1.0f + expf(dist - GAMMA));

    float* op = out + (size_t)t * DIM + lane * 2;
    atomicAdd(op,     score * tx);
    atomicAdd(op + 1, score * ty);
}

extern "C" void kernel_launch(void* const* d_in, const int* in_sizes, int n_in,
                              void* d_out, int out_size, void* d_ws, size_t ws_size,
                              hipStream_t stream) {
    const float* node_emb = (const float*)d_in[0];
    const float* edge_emb = (const float*)d_in[1];
    const int*   src      = (const int*)d_in[2];
    const int*   dst      = (const int*)d_in[3];
    float*       out      = (float*)d_out;

    int E = in_sizes[2];  // number of edges

    // Output is re-poisoned to 0xAA before every timed launch -> must zero.
    hipMemsetAsync(d_out, 0, (size_t)out_size * sizeof(float), stream);

    // 4 edges (4 waves) per 256-thread block.
    dim3 grid((E + 3) / 4);
    transe_edge_kernel<<<grid, 256, 0, stream>>>(node_emb, edge_emb, src, dst, out, E);
}

// Round 2
// 820.266 us; speedup vs baseline: 1.0239x; 1.0239x over previous
//
#include <hip/hip_runtime.h>

#define DIM 128
#define GAMMA 12.0f
#define SCAN_THREADS 1024

// --- Phase 1: histogram of in-degree per dst node (counts into `cursor`) ---
__global__ __launch_bounds__(256) void hist_kernel(const int* __restrict__ dst,
                                                   int* __restrict__ cnt, int E) {
    int e = blockIdx.x * (int)blockDim.x + (int)threadIdx.x;
    if (e < E) atomicAdd(&cnt[dst[e]], 1);
}

// --- Phase 2: single-block exclusive scan; writes offs[] and resets cnt[] to
// the same exclusive prefix so it can serve as the scatter cursor. ---
__global__ __launch_bounds__(SCAN_THREADS) void scan_kernel(int* __restrict__ cnt,
                                                            int* __restrict__ offs,
                                                            int N) {
    __shared__ int partial[SCAN_THREADS];
    int t = threadIdx.x;
    int chunk = (N + SCAN_THREADS - 1) / SCAN_THREADS;
    int lo = t * chunk;
    int hi = lo + chunk; if (hi > N) hi = N;

    int sum = 0;
    for (int i = lo; i < hi; ++i) sum += cnt[i];
    partial[t] = sum;
    __syncthreads();

    // Hillis-Steele inclusive scan over the 1024 block partials.
    for (int off = 1; off < SCAN_THREADS; off <<= 1) {
        int v = (t >= off) ? partial[t - off] : 0;
        __syncthreads();
        partial[t] += v;
        __syncthreads();
    }
    int run = (t == 0) ? 0 : partial[t - 1];
    for (int i = lo; i < hi; ++i) {
        int c = cnt[i];
        offs[i] = run;
        cnt[i]  = run;   // cursor copy for the scatter phase
        run += c;
    }
}

// --- Phase 3: bucket edge ids by dst. After this, cursor[v] == end offset. ---
__global__ __launch_bounds__(256) void scatter_kernel(const int* __restrict__ dst,
                                                      int* __restrict__ cursor,
                                                      int* __restrict__ sorted, int E) {
    int e = blockIdx.x * (int)blockDim.x + (int)threadIdx.x;
    if (e < E) {
        int pos = atomicAdd(&cursor[dst[e]], 1);
        sorted[pos] = e;
    }
}

// --- Phase 4: one 64-lane wave per dst node; register accumulation, one
// coalesced non-atomic write per node (also overwrites the 0xAA poison). ---
__global__ __launch_bounds__(256) void node_kernel(
    const float* __restrict__ node_emb,
    const float* __restrict__ edge_emb,
    const int* __restrict__ src,
    const int* __restrict__ sorted,
    const int* __restrict__ offs,
    const int* __restrict__ ends,   // == cursor after scatter
    float* __restrict__ out,
    int N)
{
    int wave = (blockIdx.x * (int)blockDim.x + (int)threadIdx.x) >> 6;
    int lane = threadIdx.x & 63;
    if (wave >= N) return;

    int start = offs[wave];
    int end   = ends[wave];

    const float2* tp = (const float2*)(node_emb + (size_t)wave * DIM);
    float2 tl = tp[lane];

    float ax = 0.0f, ay = 0.0f;
    for (int k = start; k < end; ++k) {
        int e = sorted[k];           // wave-uniform broadcast load
        int s = src[e];
        const float2* hp = (const float2*)(node_emb + (size_t)s * DIM);
        const float2* rp = (const float2*)(edge_emb + (size_t)e * DIM);
        float2 h = hp[lane];
        float2 r = rp[lane];
        float tx = h.x + r.x;
        float ty = h.y + r.y;
        float dx = tx - tl.x;
        float dy = ty - tl.y;
        float sq = dx * dx + dy * dy;
        #pragma unroll
        for (int off = 32; off > 0; off >>= 1)
            sq += __shfl_xor(sq, off, 64);
        float score = 1.0f / (1.0f + expf(sqrtf(sq) - GAMMA));
        ax += score * tx;
        ay += score * ty;
    }

    float2* op = (float2*)(out + (size_t)wave * DIM);
    op[lane] = make_float2(ax, ay);
}

extern "C" void kernel_launch(void* const* d_in, const int* in_sizes, int n_in,
                              void* d_out, int out_size, void* d_ws, size_t ws_size,
                              hipStream_t stream) {
    const float* node_emb = (const float*)d_in[0];
    const float* edge_emb = (const float*)d_in[1];
    const int*   src      = (const int*)d_in[2];
    const int*   dst      = (const int*)d_in[3];
    float*       out      = (float*)d_out;

    int E = in_sizes[2];
    int N = out_size / DIM;

    // Workspace layout: offs[N] | cursor[N] | sorted[E]
    int* offs   = (int*)d_ws;
    int* cursor = offs + N;
    int* sorted = cursor + N;

    hipMemsetAsync(cursor, 0, (size_t)N * sizeof(int), stream);
    hist_kernel<<<(E + 255) / 256, 256, 0, stream>>>(dst, cursor, E);
    scan_kernel<<<1, SCAN_THREADS, 0, stream>>>(cursor, offs, N);
    scatter_kernel<<<(E + 255) / 256, 256, 0, stream>>>(dst, cursor, sorted, E);

    // One wave per node: N waves = N*64 threads, 256 threads/block.
    dim3 grid(((size_t)N * 64 + 255) / 256);
    node_kernel<<<grid, 256, 0, stream>>>(node_emb, edge_emb, src, sorted,
                                          offs, cursor, out, N);
}

// Round 3
// 550.404 us; speedup vs baseline: 1.5259x; 1.4903x over previous
//
#include <hip/hip_runtime.h>

#define DIM 128
#define GAMMA 12.0f
#define SCAN_BLOCK 256
#define SCAN_ELEMS 1024   // 4 elements per thread

// --- Phase 1: histogram of in-degree per dst node (into `cursor`) ---
__global__ __launch_bounds__(256) void hist_kernel(const int* __restrict__ dst,
                                                   int* __restrict__ cnt, int E) {
    int e = blockIdx.x * (int)blockDim.x + (int)threadIdx.x;
    if (e < E) atomicAdd(&cnt[dst[e]], 1);
}

// --- Phase 2a: per-block totals of cnt ---
__global__ __launch_bounds__(SCAN_BLOCK) void scan_reduce_kernel(
    const int* __restrict__ cnt, int* __restrict__ blockSums, int N) {
    int b = blockIdx.x, t = threadIdx.x;
    int base = b * SCAN_ELEMS + t * 4;
    int s = 0;
    #pragma unroll
    for (int j = 0; j < 4; ++j) {
        int i = base + j;
        if (i < N) s += cnt[i];
    }
    #pragma unroll
    for (int off = 32; off > 0; off >>= 1) s += __shfl_down(s, off, 64);
    __shared__ int wsum[SCAN_BLOCK / 64];
    if ((t & 63) == 0) wsum[t >> 6] = s;
    __syncthreads();
    if (t == 0) {
        int tot = 0;
        #pragma unroll
        for (int w = 0; w < SCAN_BLOCK / 64; ++w) tot += wsum[w];
        blockSums[b] = tot;
    }
}

// --- Phase 2b: exclusive scan of the block sums (B <= 256, one block) ---
__global__ __launch_bounds__(SCAN_BLOCK) void scan_spine_kernel(
    int* __restrict__ blockSums, int B) {
    __shared__ int sh[SCAN_BLOCK];
    int t = threadIdx.x;
    int v = (t < B) ? blockSums[t] : 0;
    sh[t] = v;
    __syncthreads();
    for (int off = 1; off < SCAN_BLOCK; off <<= 1) {
        int u = (t >= off) ? sh[t - off] : 0;
        __syncthreads();
        sh[t] += u;
        __syncthreads();
    }
    if (t < B) blockSums[t] = sh[t] - v;   // exclusive
}

// --- Phase 2c: per-block rescan; writes offs[] and cursor[] (cursor aliases
// cnt: each element is read before it is overwritten, block-locally). ---
__global__ __launch_bounds__(SCAN_BLOCK) void scan_final_kernel(
    const int* __restrict__ blockSums, int* __restrict__ cnt_cursor,
    int* __restrict__ offs, int N) {
    __shared__ int sh[SCAN_BLOCK];
    int b = blockIdx.x, t = threadIdx.x;
    int base = b * SCAN_ELEMS + t * 4;
    int v[4];
    int s = 0;
    #pragma unroll
    for (int j = 0; j < 4; ++j) {
        int i = base + j;
        v[j] = (i < N) ? cnt_cursor[i] : 0;
        s += v[j];
    }
    sh[t] = s;
    __syncthreads();
    for (int off = 1; off < SCAN_BLOCK; off <<= 1) {
        int u = (t >= off) ? sh[t - off] : 0;
        __syncthreads();
        sh[t] += u;
        __syncthreads();
    }
    int run = blockSums[b] + sh[t] - s;    // exclusive prefix for this thread
    #pragma unroll
    for (int j = 0; j < 4; ++j) {
        int i = base + j;
        if (i < N) {
            offs[i] = run;
            cnt_cursor[i] = run;           // scatter cursor
        }
        run += v[j];
    }
}

// --- Phase 3: bucket edge ids by dst. After this, cursor[v] == end offset. ---
__global__ __launch_bounds__(256) void scatter_kernel(const int* __restrict__ dst,
                                                      int* __restrict__ cursor,
                                                      int* __restrict__ sorted, int E) {
    int e = blockIdx.x * (int)blockDim.x + (int)threadIdx.x;
    if (e < E) {
        int pos = atomicAdd(&cursor[dst[e]], 1);
        sorted[pos] = e;
    }
}

// --- Phase 4: one wave per dst node, 2 edges in flight per wave.
// Lanes 0-31 (half 0) take even-indexed edges, lanes 32-63 odd-indexed;
// each half-lane holds 4 dims (float4), halves combined at the end. ---
__global__ __launch_bounds__(256) void node_kernel(
    const float* __restrict__ node_emb,
    const float* __restrict__ edge_emb,
    const int* __restrict__ src,
    const int* __restrict__ sorted,
    const int* __restrict__ offs,
    const int* __restrict__ ends,
    float* __restrict__ out,
    int N)
{
    int wave = (blockIdx.x * (int)blockDim.x + (int)threadIdx.x) >> 6;
    int lane = threadIdx.x & 63;
    if (wave >= N) return;

    int half = lane >> 5;        // 0 or 1
    int hl   = lane & 31;        // lane within half: 4 dims each

    int start = offs[wave];
    int end   = ends[wave];

    const float4* tp = (const float4*)(node_emb + (size_t)wave * DIM);
    float4 tl = tp[hl];

    float ax = 0.f, ay = 0.f, az = 0.f, aw = 0.f;

    for (int k = start + half; k < end; k += 2) {
        int e = sorted[k];
        int s = src[e];
        float4 h = ((const float4*)(node_emb + (size_t)s * DIM))[hl];
        float4 r = ((const float4*)(edge_emb + (size_t)e * DIM))[hl];
        float tx = h.x + r.x, ty = h.y + r.y, tz = h.z + r.z, tw = h.w + r.w;
        float dx = tx - tl.x, dy = ty - tl.y, dz = tz - tl.z, dw = tw - tl.w;
        float sq = dx * dx + dy * dy + dz * dz + dw * dw;
        // reduce across the 32 lanes of this half (xor offsets < 32)
        #pragma unroll
        for (int off = 16; off > 0; off >>= 1)
            sq += __shfl_xor(sq, off, 64);
        float score = 1.0f / (1.0f + expf(sqrtf(sq) - GAMMA));
        ax += score * tx; ay += score * ty; az += score * tz; aw += score * tw;
    }

    // combine the two halves (lane i <-> lane i^32 hold the same 4 dims)
    ax += __shfl_xor(ax, 32, 64);
    ay += __shfl_xor(ay, 32, 64);
    az += __shfl_xor(az, 32, 64);
    aw += __shfl_xor(aw, 32, 64);

    if (half == 0) {
        float4* op = (float4*)(out + (size_t)wave * DIM);
        op[hl] = make_float4(ax, ay, az, aw);
    }
}

extern "C" void kernel_launch(void* const* d_in, const int* in_sizes, int n_in,
                              void* d_out, int out_size, void* d_ws, size_t ws_size,
                              hipStream_t stream) {
    const float* node_emb = (const float*)d_in[0];
    const float* edge_emb = (const float*)d_in[1];
    const int*   src      = (const int*)d_in[2];
    const int*   dst      = (const int*)d_in[3];
    float*       out      = (float*)d_out;

    int E = in_sizes[2];
    int N = out_size / DIM;
    int B = (N + SCAN_ELEMS - 1) / SCAN_ELEMS;   // 98 for N=100000

    // Workspace: offs[N] | cursor[N] | sorted[E] | blockSums[SCAN_BLOCK]
    int* offs      = (int*)d_ws;
    int* cursor    = offs + N;
    int* sorted    = cursor + N;
    int* blockSums = sorted + E;

    hipMemsetAsync(cursor, 0, (size_t)N * sizeof(int), stream);
    hist_kernel<<<(E + 255) / 256, 256, 0, stream>>>(dst, cursor, E);
    scan_reduce_kernel<<<B, SCAN_BLOCK, 0, stream>>>(cursor, blockSums, N);
    scan_spine_kernel<<<1, SCAN_BLOCK, 0, stream>>>(blockSums, B);
    scan_final_kernel<<<B, SCAN_BLOCK, 0, stream>>>(blockSums, cursor, offs, N);
    scatter_kernel<<<(E + 255) / 256, 256, 0, stream>>>(dst, cursor, sorted, E);

    dim3 grid(((size_t)N * 64 + 255) / 256);
    node_kernel<<<grid, 256, 0, stream>>>(node_emb, edge_emb, src, sorted,
                                          offs, cursor, out, N);
}